// Round 5
// baseline (95.092 us; speedup 1.0000x reference)
//
#include <hip/hip_runtime.h>
#include <math.h>

#define BB 4
#define HH 512
#define WW 512
#define HWSZ (HH * WW)

// ---- edt_cols tiling: 512 threads = TCOLS cols x TCH chunks, CROWS rows/chunk
#define TCOLS 16
#define TCH   32
#define CROWS 16
#define COLS_BLOCKS (BB * (WW / TCOLS))   // 128
#define ROWS_BLOCKS (BB * HH)             // 2048
#define BIGR 0x100000                     // "no seed" row sentinel for min-scans

// ws layout:
//   [0,    512)    int flags[128]      (one per edt_cols block: batch has fg)
//   [32768, +4MB)  u32 gpack[BB*HH*WW] (low16 = g seed=mask, high16 = g seed=~mask)

// ---------------------------------------------------------------------------
// Pass 1: per-column 1D nearest-seed distances for BOTH seeds (mask, ~mask).
// Thread (c, ch) owns 16 rows of one column -> u16 row bitmask (16 independent
// loads for ILP). Chunk summaries (first/last seed row) to LDS; 8 waves run
// 5-step shuffle max/min scans to get chunk-boundary prefixes; per-row
// distances via clz/ctz on the register mask. Also: block presence flag
// (popc-reduce) for the 'mask.sum() > 0' guard, and block 0 zeroes out[0]
// (poisoned 0xAA by the harness) so pass 2 can accumulate atomically.
// ---------------------------------------------------------------------------
__global__ __launch_bounds__(512) void edt_cols_kernel(
    const int* __restrict__ target,
    unsigned int* __restrict__ gpack,
    int* __restrict__ flags,
    float* __restrict__ out)
{
    int blk = blockIdx.x;          // b*32 + tile
    int b = blk >> 5;
    int tile = blk & 31;
    int tid = threadIdx.x;
    int c = tid & (TCOLS - 1);     // column within tile
    int ch = tid >> 4;             // chunk index 0..31
    int j = tile * TCOLS + c;
    int r0 = ch * CROWS;

    if (blk == 0 && tid == 0) out[0] = 0.0f;   // visible to pass 2 (stream order)

    const int* t = target + b * HWSZ + j;

    unsigned int maskN = 0;        // 16 independent loads -> row bitmask
#pragma unroll
    for (int i = 0; i < CROWS; ++i)
        maskN |= (unsigned int)(t[(r0 + i) * WW] == 1) << i;
    unsigned int maskP = maskN ^ 0xFFFFu;

    __shared__ int sLN[TCH][TCOLS], sFN[TCH][TCOLS];   // last/first seed row
    __shared__ int sLP[TCH][TCOLS], sFP[TCH][TCOLS];
    __shared__ int sBN[TCH][TCOLS], sAN[TCH][TCOLS];   // before/after prefixes
    __shared__ int sBP[TCH][TCOLS], sAP[TCH][TCOLS];
    __shared__ int sCnt;

    sLN[ch][c] = maskN ? (r0 + 31 - __builtin_clz(maskN)) : -1;
    sFN[ch][c] = maskN ? (r0 + __builtin_ctz(maskN))      : BIGR;
    sLP[ch][c] = maskP ? (r0 + 31 - __builtin_clz(maskP)) : -1;
    sFP[ch][c] = maskP ? (r0 + __builtin_ctz(maskP))      : BIGR;

    int cnt = __popc(maskN);       // wave reduce, then one LDS atomic per wave
#pragma unroll
    for (int off = 32; off > 0; off >>= 1) cnt += __shfl_down(cnt, off, 64);
    if (tid == 0) sCnt = 0;
    __syncthreads();
    if ((tid & 63) == 0) atomicAdd(&sCnt, cnt);

    // shuffle scans: wave w handles columns 2w, 2w+1 (32 chunks in 32 lanes)
    int w = tid >> 6, lane = tid & 63;
    int cc = 2 * w + (lane >> 5);
    int c2 = lane & 31;            // chunk index inside the scan
    int iLN = sLN[c2][cc], iLP = sLP[c2][cc];
    int iFN = sFN[c2][cc], iFP = sFP[c2][cc];
#pragma unroll
    for (int d = 1; d < 32; d <<= 1) {          // inclusive forward max-scan
        int uLN = __shfl_up(iLN, d, 64);
        int uLP = __shfl_up(iLP, d, 64);
        if (c2 >= d) { iLN = max(iLN, uLN); iLP = max(iLP, uLP); }
    }
#pragma unroll
    for (int d = 1; d < 32; d <<= 1) {          // inclusive backward min-scan
        int dFN = __shfl_down(iFN, d, 64);
        int dFP = __shfl_down(iFP, d, 64);
        if (c2 + d < 32) { iFN = min(iFN, dFN); iFP = min(iFP, dFP); }
    }
    int bLN = __shfl_up(iLN, 1, 64);  if (c2 == 0)  bLN = -1;    // exclusive
    int bLP = __shfl_up(iLP, 1, 64);  if (c2 == 0)  bLP = -1;
    int aFN = __shfl_down(iFN, 1, 64); if (c2 == 31) aFN = BIGR;
    int aFP = __shfl_down(iFP, 1, 64); if (c2 == 31) aFP = BIGR;
    sBN[c2][cc] = bLN; sBP[c2][cc] = bLP;
    sAN[c2][cc] = aFN; sAP[c2][cc] = aFP;
    __syncthreads();

    int befN = sBN[ch][c], befP = sBP[ch][c];
    int aftN = sAN[ch][c], aftP = sAP[ch][c];
    unsigned int* gp = gpack + b * HWSZ + j;

#pragma unroll
    for (int i = 0; i < CROWS; ++i) {
        int row = r0 + i;
        unsigned int belowN = maskN << (31 - i);   // bit31 = row i
        unsigned int aboveN = maskN >> i;          // bit0  = row i
        unsigned int dfN = belowN ? (unsigned int)__builtin_clz(belowN)
                                  : (befN >= 0 ? (unsigned int)(row - befN) : 0xFFFFu);
        unsigned int dbN = aboveN ? (unsigned int)__builtin_ctz(aboveN)
                                  : (aftN < BIGR ? (unsigned int)(aftN - row) : 0xFFFFu);
        unsigned int gN = dfN < dbN ? dfN : dbN;
        if (gN > 0xFFFFu) gN = 0xFFFFu;

        unsigned int belowP = maskP << (31 - i);
        unsigned int aboveP = maskP >> i;
        unsigned int dfP = belowP ? (unsigned int)__builtin_clz(belowP)
                                  : (befP >= 0 ? (unsigned int)(row - befP) : 0xFFFFu);
        unsigned int dbP = aboveP ? (unsigned int)__builtin_ctz(aboveP)
                                  : (aftP < BIGR ? (unsigned int)(aftP - row) : 0xFFFFu);
        unsigned int gP = dfP < dbP ? dfP : dbP;
        if (gP > 0xFFFFu) gP = 0xFFFFu;

        gp[row * WW] = gN | (gP << 16);
    }

    if (tid == 0) flags[blk] = (sCnt > 0);
}

// ---------------------------------------------------------------------------
// Pass 2 (final): one WAVE per image row. Lane k owns columns 8k..8k+7.
// Staging: 2x uint4 gpack + 4x float4 pred per lane (fully coalesced, issued
// back-to-back for ILP). Exact expanding-ring search (early exit when r^2 >=
// all 16 running bests; clamped edge indices only add over-estimates, so the
// min stays exact). dmap = sqrt(d2n)-sqrt(d2p) weighted by sigmoid(x1-x0).
// Reduction: 6 shuffles -> lane 0 does ONE guarded fp32 atomicAdd of the
// pre-scaled partial into out[0] (zeroed by pass 1). Presence guard read from
// pass-1 flags via ballot. No fences, no tickets, no extra dispatch.
// ---------------------------------------------------------------------------
#define SK(x) ((x) + ((x) >> 5))

__global__ __launch_bounds__(64) void edt_rows_kernel(
    const unsigned int* __restrict__ gpack,
    const float* __restrict__ pred,
    const int* __restrict__ flags,
    float* __restrict__ out)
{
    __shared__ float g2n[SK(511) + 1];
    __shared__ float g2p[SK(511) + 1];

    int bi = blockIdx.x;            // b*HH + i
    int b = bi >> 9;
    int i = bi & (HH - 1);
    int k = threadIdx.x;            // lane 0..63
    int j0 = 8 * k;

    // presence guard: 32 flags per batch, ballot across the wave
    int f = flags[(b << 5) + (k & 31)];
    unsigned long long pres = __ballot(f != 0);

    const float* p0 = pred + (b * 2 + 0) * HWSZ + i * WW + j0;
    const float* p1 = pred + (b * 2 + 1) * HWSZ + i * WW + j0;
    float4 a0 = *(const float4*)(p0);       // issued early, consumed late
    float4 a1 = *(const float4*)(p0 + 4);
    float4 c0 = *(const float4*)(p1);
    float4 c1 = *(const float4*)(p1 + 4);

    const uint4* gp4 = (const uint4*)(gpack + b * HWSZ + i * WW);
    uint4 ga = gp4[k];          // u32 indices 4k .. 4k+3
    uint4 gb = gp4[k + 64];     // u32 indices 256+4k .. 256+4k+3

    unsigned int va[4] = {ga.x, ga.y, ga.z, ga.w};
    unsigned int vb[4] = {gb.x, gb.y, gb.z, gb.w};
#pragma unroll
    for (int t = 0; t < 4; ++t) {
        int idx = 4 * k + t;
        unsigned int gN = va[t] & 0xFFFFu, gP = va[t] >> 16;
        g2n[SK(idx)] = (gN == 0xFFFFu) ? 1e18f : (float)(gN * gN);
        g2p[SK(idx)] = (gP == 0xFFFFu) ? 1e18f : (float)(gP * gP);
        int idx2 = 256 + 4 * k + t;
        gN = vb[t] & 0xFFFFu; gP = vb[t] >> 16;
        g2n[SK(idx2)] = (gN == 0xFFFFu) ? 1e18f : (float)(gN * gN);
        g2p[SK(idx2)] = (gP == 0xFFFFu) ? 1e18f : (float)(gP * gP);
    }
    __syncthreads();

    float bn[8], bp[8];
#pragma unroll
    for (int jj = 0; jj < 8; ++jj) {
        bn[jj] = g2n[SK(j0 + jj)];
        bp[jj] = g2p[SK(j0 + jj)];
    }
    for (int r = 1; r < WW; ++r) {
        float sq = (float)(r * r);
        float mx = 0.0f;
#pragma unroll
        for (int jj = 0; jj < 8; ++jj) mx = fmaxf(mx, fmaxf(bn[jj], bp[jj]));
        if (sq >= mx) break;        // all 8 columns of this lane converged
#pragma unroll
        for (int jj = 0; jj < 8; ++jj) {
            int kl = j0 + jj - r; kl = kl < 0 ? 0 : kl;
            int kr = j0 + jj + r; kr = kr > (WW - 1) ? (WW - 1) : kr;
            int skl = SK(kl), skr = SK(kr);
            bn[jj] = fminf(bn[jj], sq + g2n[skl]);
            bp[jj] = fminf(bp[jj], sq + g2p[skl]);
            bn[jj] = fminf(bn[jj], sq + g2n[skr]);
            bp[jj] = fminf(bp[jj], sq + g2p[skr]);
        }
    }

    float x0[8] = {a0.x, a0.y, a0.z, a0.w, a1.x, a1.y, a1.z, a1.w};
    float x1[8] = {c0.x, c0.y, c0.z, c0.w, c1.x, c1.y, c1.z, c1.w};
    float acc = 0.0f;
#pragma unroll
    for (int jj = 0; jj < 8; ++jj) {
        float dist = sqrtf(bn[jj]) - sqrtf(bp[jj]);          // negEDT - posEDT
        float prob = 1.0f / (1.0f + __expf(x0[jj] - x1[jj]));  // softmax class-1
        acc += prob * dist;
    }
#pragma unroll
    for (int off = 32; off > 0; off >>= 1) acc += __shfl_down(acc, off, 64);

    // one fire-and-forget device-scope atomic per block; guard = 'mask.sum()>0'
    if (k == 0 && pres)
        atomicAdd(out, acc * (1.0f / 2097152.0f));  // mean over B*C*H*W
}

extern "C" void kernel_launch(void* const* d_in, const int* in_sizes, int n_in,
                              void* d_out, int out_size, void* d_ws, size_t ws_size,
                              hipStream_t stream) {
    const float* pred = (const float*)d_in[0];
    const int* target = (const int*)d_in[1];
    float* out = (float*)d_out;

    char* ws = (char*)d_ws;
    int* flags = (int*)(ws + 0);
    unsigned int* gpack = (unsigned int*)(ws + 32768);

    edt_cols_kernel<<<COLS_BLOCKS, 512, 0, stream>>>(target, gpack, flags, out);
    edt_rows_kernel<<<ROWS_BLOCKS, 64, 0, stream>>>(gpack, pred, flags, out);
}